// Round 5
// baseline (411.670 us; speedup 1.0000x reference)
//
#include <hip/hip_runtime.h>
#include <stdint.h>

// DomainAttentionLayer: out = softmax((x Wq^T + bq)(dx Wk^T + bk)^T / sqrt(D)) (dx Wv^T + bv)
// N = M = 8192, D = 512, fp32 in/out; internal compute bf16 MFMA.
//
// Pipeline:
//   0) prep_w    : W fp32 -> bf16 (once)
//   1) qkv_proj  : bf16 GEMMs, bias fused; Q pre-scaled by log2(e)/sqrt(D); V stored VT[D][M]
//   2) flash_attn: fused online-softmax attention, split-m x SPLITS partials.
//                  R3 structure (proven stable through graph-replay revalidation),
//                  with ONE graft: PV B-operands (V) loaded directly from global/L2
//                  into registers inside PV (d-cols are wave-exclusive; the LDS
//                  round-trip bought nothing). Removes the VT DMA + 16 b128
//                  LDS reads/wave-iter + one barrier. K staging unchanged.
//   3) combine   : exact log-sum-exp merge of partials -> fp32 out

#define DEV __device__ __forceinline__

typedef short short8 __attribute__((ext_vector_type(8)));     // 8 bf16 (4 VGPRs) MFMA frag
typedef float floatx4 __attribute__((ext_vector_type(4)));    // MFMA accum
typedef unsigned int uintx4 __attribute__((ext_vector_type(4)));
typedef unsigned short ushortx4 __attribute__((ext_vector_type(4)));

constexpr int NN = 8192;
constexpr int MM = 8192;
constexpr int DD = 512;
constexpr float SCALE2 = 0.0637587160f;         // log2(e) / sqrt(512), folded into Q

#define NEG_INF (-__builtin_inff())

#if defined(__has_builtin)
#if __has_builtin(__builtin_amdgcn_exp2f)
#define EXP2F(x) __builtin_amdgcn_exp2f(x)
#else
#define EXP2F(x) exp2f(x)
#endif
#else
#define EXP2F(x) exp2f(x)
#endif

DEV unsigned short f2bf(float f) {              // RNE fp32 -> bf16 bits
  unsigned u = __builtin_bit_cast(unsigned, f);
  return (unsigned short)((u + 0x7FFFu + ((u >> 16) & 1u)) >> 16);
}
DEV float bf2f(unsigned short h) {
  unsigned u = ((unsigned)h) << 16;
  return __builtin_bit_cast(float, u);
}

// TBAA-safe vector ld/st (memcpy compiles to single b128/b64 with assumed alignment)
DEV short8 ld_s8(const void* p) {
  short8 v; __builtin_memcpy(&v, __builtin_assume_aligned(p, 16), 16); return v;
}
DEV uintx4 ld_u4(const void* p) {
  uintx4 v; __builtin_memcpy(&v, __builtin_assume_aligned(p, 16), 16); return v;
}
DEV void st_u4(void* p, uintx4 v) {
  __builtin_memcpy(__builtin_assume_aligned(p, 16), &v, 16);
}
DEV void st_us4(void* p, ushortx4 v) {
  __builtin_memcpy(__builtin_assume_aligned(p, 8), &v, 8);
}
DEV float4 ld_f4(const void* p) {
  float4 v; __builtin_memcpy(&v, __builtin_assume_aligned(p, 16), 16); return v;
}

DEV void async_lds16(const void* g, const void* l) {  // global -> LDS DMA, 16B/lane
  __builtin_amdgcn_global_load_lds(
      (const __attribute__((address_space(1))) unsigned int*)g,
      (__attribute__((address_space(3))) unsigned int*)l, 16, 0, 0);
}

// ---------------------------------------------------------------------------
// Kernel 0: W fp32 -> bf16, once. grid (128, 1, 3), block 256, 8 elems/thread.
// ---------------------------------------------------------------------------
__global__ void prep_w(const float* __restrict__ Wq, const float* __restrict__ Wk,
                       const float* __restrict__ Wv, unsigned short* __restrict__ Wb) {
  const int z = blockIdx.z;
  const float* src = (z == 0) ? Wq : (z == 1) ? Wk : Wv;
  unsigned short* dst = Wb + (size_t)z * DD * DD;
  size_t idx = ((size_t)blockIdx.x * 256 + threadIdx.x) * 8;
  float4 a = ld_f4(src + idx);
  float4 b = ld_f4(src + idx + 4);
  ushortx4 lo = {f2bf(a.x), f2bf(a.y), f2bf(a.z), f2bf(a.w)};
  ushortx4 hi = {f2bf(b.x), f2bf(b.y), f2bf(b.z), f2bf(b.w)};
  st_us4(dst + idx, lo);
  st_us4(dst + idx + 4, hi);
}

// ---------------------------------------------------------------------------
// Kernel 1: QKV projection. grid (128, 2, 3), block 256. Tile 64 rows x 256 cols,
// BK=64. LDS xor-swizzled (chunk ^= row&7) -> conflict-free b128 frag reads.
// z=0: Q (scaled by SCALE2) -> Qb[N][D]; z=1: K -> Kb[M][D]; z=2: V -> VTb[D][M].
// ---------------------------------------------------------------------------
__global__ __launch_bounds__(256, 2)
void qkv_proj(const float* __restrict__ x, const float* __restrict__ dx,
              const unsigned short* __restrict__ Wb,
              const float* __restrict__ bq, const float* __restrict__ bk,
              const float* __restrict__ bv,
              unsigned short* __restrict__ Qb, unsigned short* __restrict__ Kb,
              unsigned short* __restrict__ VTb) {
  const int z = blockIdx.z;
  const float* A = (z == 0) ? x : dx;
  const unsigned short* W = Wb + (size_t)z * DD * DD;
  const float* bias = (z == 0) ? bq : (z == 1) ? bk : bv;

  const int r0 = blockIdx.x * 64;
  const int c0 = blockIdx.y * 256;
  const int tid = threadIdx.x;
  const int lane = tid & 63;
  const int wave = tid >> 6;
  const int lr = lane & 15;
  const int quad = lane >> 4;

  __shared__ __align__(16) unsigned short As[64 * 64];   //  8 KB
  __shared__ __align__(16) unsigned short Ws[256 * 64];  // 32 KB

  floatx4 o[16];
#pragma unroll
  for (int i = 0; i < 16; ++i) o[i] = {0.f, 0.f, 0.f, 0.f};

  for (int k0 = 0; k0 < DD; k0 += 64) {
    // stage A tile (fp32 -> bf16): 64 rows x 64 k, 4 float4 per thread
#pragma unroll
    for (int i = 0; i < 4; ++i) {
      int idx = i * 256 + tid;
      int r = idx >> 4, c4 = idx & 15;
      float4 v = ld_f4(A + (size_t)(r0 + r) * DD + k0 + c4 * 4);
      ushortx4 pk = {f2bf(v.x), f2bf(v.y), f2bf(v.z), f2bf(v.w)};
      st_us4(&As[r * 64 + (((c4 >> 1) ^ (r & 7)) * 8) + (c4 & 1) * 4], pk);
    }
    // stage W tile (bf16, no convert): 256 rows x 64 k, 8 x 16B per thread
#pragma unroll
    for (int i = 0; i < 8; ++i) {
      int idx = i * 256 + tid;
      int r = idx >> 3, c = idx & 7;
      uintx4 v = ld_u4(W + (size_t)(c0 + r) * DD + k0 + c * 8);
      st_u4(&Ws[r * 64 + ((c ^ (r & 7)) * 8)], v);
    }
    __syncthreads();

    short8 a[2];
#pragma unroll
    for (int ks = 0; ks < 2; ++ks)
      a[ks] = ld_s8(&As[(wave * 16 + lr) * 64 + (((ks * 4 + quad) ^ (lr & 7)) * 8)]);
#pragma unroll
    for (int ct = 0; ct < 16; ++ct) {
#pragma unroll
      for (int ks = 0; ks < 2; ++ks) {
        short8 b = ld_s8(&Ws[(ct * 16 + lr) * 64 + (((ks * 4 + quad) ^ (lr & 7)) * 8)]);
        o[ct] = __builtin_amdgcn_mfma_f32_16x16x32_bf16(a[ks], b, o[ct], 0, 0, 0);
      }
    }
    __syncthreads();
  }

  // epilogue: bias (+Q scale), store. C layout: col = lr, row = quad*4 + reg.
#pragma unroll
  for (int ct = 0; ct < 16; ++ct) {
    int col = c0 + ct * 16 + lr;
    float bv_ = bias[col];
    int rowb = r0 + wave * 16 + quad * 4;
    if (z == 2) {  // VT[col][row], 4 consecutive rows -> 8B store
      ushortx4 pk = {f2bf(o[ct][0] + bv_), f2bf(o[ct][1] + bv_),
                     f2bf(o[ct][2] + bv_), f2bf(o[ct][3] + bv_)};
      st_us4(VTb + (size_t)col * MM + rowb, pk);
    } else {
      unsigned short* Outp = (z == 0) ? Qb : Kb;
      float sc = (z == 0) ? SCALE2 : 1.f;
#pragma unroll
      for (int r = 0; r < 4; ++r)
        Outp[(size_t)(rowb + r) * DD + col] = f2bf((o[ct][r] + bv_) * sc);
    }
  }
}

// ---------------------------------------------------------------------------
// Kernel 2: flash attention. 1-D grid (N/64 * SPLITS_), block 256, 2 blocks/CU.
// Block remap: split = lin & (SPLITS_-1) -- with round-robin XCD = lin%8 this
// pins each XCD to one split -> K/VT slices L2-resident.
// S phase: wave w owns q-rows [16w,16w+16) (softmax state wave-private).
// PV phase (D-split): wave w computes O[all 64 rows][cols 128w..128w+128);
// P (64x64) + alphas shared via LDS; V B-frags loaded per-ks directly from
// global (L2) into registers -- d-cols are wave-exclusive, no LDS round-trip.
// K staged by global_load_lds (row-exact DMA), drained at the next barrier
// (R3-proven pattern). LDS 76,544 B. Regs: o 128 + qf 64 + transients -> no spill.
// ---------------------------------------------------------------------------
template <int SPLITS_, int LOG2S_>
__global__ __launch_bounds__(256, 2)
void flash_attn(const unsigned short* __restrict__ Qb,
                const unsigned short* __restrict__ Kb,
                const unsigned short* __restrict__ VTb,
                unsigned short* __restrict__ Opart,
                float* __restrict__ Mpart, float* __restrict__ Lpart) {
  constexpr int MT = MM / SPLITS_;
  constexpr int ITERS = MT / 64;
  const int lin = blockIdx.x;
  const int split = lin & (SPLITS_ - 1);
  const int n0 = (lin >> LOG2S_) * 64;
  const int m_begin = split * MT;

  const int tid = threadIdx.x;
  const int lane = tid & 63;
  const int wave = tid >> 6;
  const int lr = lane & 15;
  const int quad = lane >> 4;

  // sK: K rows stride 520 us (1024B DMA row + 16B pad -> frag-read banks spread)
  __shared__ __align__(16) unsigned short sK[64 * 520];    // 66,560 B
  __shared__ __align__(16) unsigned short sP[64 * 76];     //  9,728 B
  __shared__ __align__(16) float sAlpha[64];               //    256 B

  // resident Q fragments: wave's 16 rows x 512 k (64 VGPRs), pre-scaled by SCALE2
  short8 qf[16];
  {
    const unsigned short* qptr = Qb + (size_t)(n0 + wave * 16 + lr) * DD + quad * 8;
#pragma unroll
    for (int ks = 0; ks < 16; ++ks) qf[ks] = ld_s8(qptr + ks * 32);
  }

  floatx4 o[32];  // [rt*8+ct] : O rows rt*16+quad*4+reg, col wave*128+ct*16+lr
#pragma unroll
  for (int i = 0; i < 32; ++i) o[i] = {0.f, 0.f, 0.f, 0.f};
  float mrow[4] = {NEG_INF, NEG_INF, NEG_INF, NEG_INF};
  float lrow[4] = {0.f, 0.f, 0.f, 0.f};

  for (int it = 0; it < ITERS; ++it) {
    const int m0 = m_begin + it * 64;

    // ---- stage K tile: one DMA per row (64 lanes x 16B = exactly 1024B row)
#pragma unroll
    for (int i = 0; i < 16; ++i) {
      const int r = wave * 16 + i;  // wave-uniform LDS dest
      async_lds16(Kb + (size_t)(m0 + r) * DD + lane * 8, &sK[r * 520]);
    }
    __syncthreads();  // BAR1: drains DMA -> K visible; prior iter's PV done with sP

    // ---- S = Q K^T (wave: its 16 rows x 64 cols), logits already in log2 units
    floatx4 s[4];
#pragma unroll
    for (int ct = 0; ct < 4; ++ct) s[ct] = {0.f, 0.f, 0.f, 0.f};
#pragma unroll
    for (int ks = 0; ks < 16; ++ks) {
      const unsigned short* kb = &sK[ks * 32 + quad * 8];
#pragma unroll
      for (int ct = 0; ct < 4; ++ct) {
        short8 b = ld_s8(kb + (ct * 16 + lr) * 520);
        s[ct] = __builtin_amdgcn_mfma_f32_16x16x32_bf16(qf[ks], b, s[ct], 0, 0, 0);
      }
    }

    // ---- online softmax (rows quad*4+r, cols across the 16 lanes of the quad)
    float alpha[4];
#pragma unroll
    for (int r = 0; r < 4; ++r) {
      float mx = fmaxf(fmaxf(s[0][r], s[1][r]), fmaxf(s[2][r], s[3][r]));
      mx = fmaxf(mx, __shfl_xor(mx, 1));
      mx = fmaxf(mx, __shfl_xor(mx, 2));
      mx = fmaxf(mx, __shfl_xor(mx, 4));
      mx = fmaxf(mx, __shfl_xor(mx, 8));
      float mnew = fmaxf(mrow[r], mx);
      alpha[r] = EXP2F(mrow[r] - mnew);  // first iter: exp2(-inf) = 0
      mrow[r] = mnew;
      float rs = 0.f;
#pragma unroll
      for (int ct = 0; ct < 4; ++ct) {
        float p = EXP2F(s[ct][r] - mnew);
        s[ct][r] = p;
        rs += p;
      }
      rs += __shfl_xor(rs, 1);
      rs += __shfl_xor(rs, 2);
      rs += __shfl_xor(rs, 4);
      rs += __shfl_xor(rs, 8);
      lrow[r] = lrow[r] * alpha[r] + rs;
    }
    if (lr == 0) {
#pragma unroll
      for (int r = 0; r < 4; ++r) sAlpha[wave * 16 + quad * 4 + r] = alpha[r];
    }

    // ---- P (C layout) -> shared LDS bf16 [64][76]
#pragma unroll
    for (int ct = 0; ct < 4; ++ct)
#pragma unroll
      for (int r = 0; r < 4; ++r)
        sP[(wave * 16 + quad * 4 + r) * 76 + ct * 16 + lr] = f2bf(s[ct][r]);

    __syncthreads();  // BAR2: sP + sAlpha visible (also: all waves done reading sK)

    // ---- rescale O by all-row alphas (shared, b128 loads)
    floatx4 af[4];
#pragma unroll
    for (int rt = 0; rt < 4; ++rt) {
      float4 t = ld_f4(&sAlpha[rt * 16 + quad * 4]);
      af[rt] = {t.x, t.y, t.z, t.w};
    }
    bool need = false;
#pragma unroll
    for (int rt = 0; rt < 4; ++rt)
#pragma unroll
      for (int r = 0; r < 4; ++r) need = need || (af[rt][r] < 1.f);
    if (__any(need)) {
#pragma unroll
      for (int rt = 0; rt < 4; ++rt)
#pragma unroll
        for (int ct = 0; ct < 8; ++ct)
#pragma unroll
          for (int r = 0; r < 4; ++r) o[rt * 8 + ct][r] *= af[rt][r];
    }

    // ---- O += P V (D-split): A = P rows (all 64) from LDS,
    //      B = V[m][dcol] direct from global/L2 (wave's 128 d-cols)
    const unsigned short* vbase =
        VTb + (size_t)(wave * 128 + lr) * MM + m0 + quad * 8;
#pragma unroll
    for (int ks = 0; ks < 2; ++ks) {
      short8 pa[4];
#pragma unroll
      for (int rt = 0; rt < 4; ++rt)
        pa[rt] = ld_s8(&sP[(rt * 16 + lr) * 76 + ks * 32 + quad * 8]);
      short8 vf[8];
#pragma unroll
      for (int ct = 0; ct < 8; ++ct)
        vf[ct] = ld_s8(vbase + (size_t)(ct * 16) * MM + ks * 32);
#pragma unroll
      for (int ct = 0; ct < 8; ++ct) {
#pragma unroll
        for (int rt = 0; rt < 4; ++rt)
          o[rt * 8 + ct] = __builtin_amdgcn_mfma_f32_16x16x32_bf16(pa[rt], vf[ct],
                                                                   o[rt * 8 + ct], 0, 0, 0);
      }
    }
    __syncthreads();  // BAR3: sP/sAlpha/sK free for next iter
  }

  // ---- epilogue: unnormalized partials (D-split layout)
  unsigned short* op = Opart + (size_t)split * NN * DD;
#pragma unroll
  for (int rt = 0; rt < 4; ++rt)
#pragma unroll
    for (int ct = 0; ct < 8; ++ct) {
      int row = n0 + rt * 16 + quad * 4;
      int col = wave * 128 + ct * 16 + lr;
#pragma unroll
      for (int r = 0; r < 4; ++r)
        op[(size_t)(row + r) * DD + col] = f2bf(o[rt * 8 + ct][r]);
    }
  const int grow = n0 + wave * 16 + quad * 4;
  if (lr == 0) {
#pragma unroll
    for (int r = 0; r < 4; ++r) {
      Mpart[split * NN + grow + r] = mrow[r];
      Lpart[split * NN + grow + r] = lrow[r];
    }
  }
}

// ---------------------------------------------------------------------------
// Kernel 3: exact softmax merge of SPLITS partials. 8 elems/thread, b128 I/O.
// grid (N*D/2048), block 256.
// ---------------------------------------------------------------------------
template <int SPLITS_>
__global__ void combine_kernel(const unsigned short* __restrict__ Op,
                               const float* __restrict__ Mp,
                               const float* __restrict__ Lp,
                               float* __restrict__ out) {
  constexpr size_t NDv = (size_t)NN * DD;
  size_t base = ((size_t)blockIdx.x * 256 + threadIdx.x) * 8;
  int n = (int)(base >> 9);
  float mv[SPLITS_];
  float ms = NEG_INF;
#pragma unroll
  for (int s = 0; s < SPLITS_; ++s) {
    mv[s] = Mp[s * NN + n];
    ms = fmaxf(ms, mv[s]);
  }
  float num[8];
#pragma unroll
  for (int j = 0; j < 8; ++j) num[j] = 0.f;
  float den = 0.f;
#pragma unroll
  for (int s = 0; s < SPLITS_; ++s) {
    float w = EXP2F(mv[s] - ms);
    den += w * Lp[s * NN + n];
    uintx4 u = ld_u4(Op + s * NDv + base);
#pragma unroll
    for (int j = 0; j < 4; ++j) {
      num[2 * j]     += w * bf2f((unsigned short)(u[j] & 0xffffu));
      num[2 * j + 1] += w * bf2f((unsigned short)(u[j] >> 16));
    }
  }
  float inv = 1.f / den;
  float4 o0 = {num[0] * inv, num[1] * inv, num[2] * inv, num[3] * inv};
  float4 o1 = {num[4] * inv, num[5] * inv, num[6] * inv, num[7] * inv};
  __builtin_memcpy(__builtin_assume_aligned(out + base, 16), &o0, 16);
  __builtin_memcpy(__builtin_assume_aligned(out + base + 4, 16), &o1, 16);
}

// ---------------------------------------------------------------------------
extern "C" void kernel_launch(void* const* d_in, const int* in_sizes, int n_in,
                              void* d_out, int out_size, void* d_ws, size_t ws_size,
                              hipStream_t stream) {
  const float* x  = (const float*)d_in[0];
  const float* dx = (const float*)d_in[1];
  const float* Wq = (const float*)d_in[2];
  const float* bq = (const float*)d_in[3];
  const float* Wk = (const float*)d_in[4];
  const float* bk = (const float*)d_in[5];
  const float* Wv = (const float*)d_in[6];
  const float* bv = (const float*)d_in[7];
  float* out = (float*)d_out;

  const size_t ND = (size_t)NN * DD;          // 4,194,304
  const size_t WBE = (size_t)3 * DD * DD;     //   786,432
  unsigned short* Qb  = (unsigned short*)d_ws;     // bf16, ND (pre-scaled)
  unsigned short* Kb  = Qb + ND;                   // bf16, ND
  unsigned short* VTb = Kb + ND;                   // bf16, ND (transposed V)
  unsigned short* Wb  = VTb + ND;                  // bf16, 3*D*D
  unsigned short* Op  = Wb + WBE;                  // bf16, splits*ND partial O

  auto bytes_for = [&](size_t S) {
    return (3 * ND + WBE + S * ND) * 2 + S * (size_t)NN * 8;
  };
  const int splits = (ws_size >= bytes_for(4)) ? 4 : 2;  // ws_size fixed -> same every call
  float* Mp = (float*)(Op + (size_t)splits * ND);
  float* Lp = Mp + (size_t)splits * NN;

  hipLaunchKernelGGL(prep_w, dim3(DD * DD / 2048, 1, 3), dim3(256), 0, stream,
                     Wq, Wk, Wv, Wb);
  hipLaunchKernelGGL(qkv_proj, dim3(NN / 64, 2, 3), dim3(256), 0, stream,
                     x, dx, Wb, bq, bk, bv, Qb, Kb, VTb);
  if (splits == 4) {
    hipLaunchKernelGGL((flash_attn<4, 2>), dim3(NN / 64 * 4), dim3(256), 0, stream,
                       Qb, Kb, VTb, Op, Mp, Lp);
    hipLaunchKernelGGL(combine_kernel<4>, dim3((unsigned)(ND / 2048)), dim3(256), 0, stream,
                       Op, Mp, Lp, out);
  } else {
    hipLaunchKernelGGL((flash_attn<2, 1>), dim3(NN / 64 * 2), dim3(256), 0, stream,
                       Qb, Kb, VTb, Op, Mp, Lp);
    hipLaunchKernelGGL(combine_kernel<2>, dim3((unsigned)(ND / 2048)), dim3(256), 0, stream,
                       Op, Mp, Lp, out);
  }
}

// Round 6
// 351.204 us; speedup vs baseline: 1.1722x; 1.1722x over previous
//
#include <hip/hip_runtime.h>
#include <stdint.h>

// DomainAttentionLayer: out = softmax((x Wq^T + bq)(dx Wk^T + bk)^T / sqrt(D)) (dx Wv^T + bv)
// N = M = 8192, D = 512, fp32 in/out; internal compute bf16 MFMA.
//
// Pipeline:
//   0) prep_w    : W fp32 -> bf16 (once)
//   1) qkv_proj  : bf16 GEMMs, bias fused; Q pre-scaled by log2(e)/sqrt(D); V stored VT[D][M]
//   2) flash_attn: fused online-softmax attention, split-m partials.
//                  R6: BN=128 q-rows per block (8 waves x 16 rows), BM=64, 1 block/CU.
//                  Same 4-barrier phase order as R3 (proven race-free); the K-tile
//                  and VT-tile are amortized over 2x the q-rows -> per-row LDS
//                  demand -18%, barriers and DMA bytes per row halved.
//   3) combine   : exact log-sum-exp merge of partials -> fp32 out

#define DEV __device__ __forceinline__

typedef short short8 __attribute__((ext_vector_type(8)));     // 8 bf16 (4 VGPRs) MFMA frag
typedef float floatx4 __attribute__((ext_vector_type(4)));    // MFMA accum
typedef unsigned int uintx4 __attribute__((ext_vector_type(4)));
typedef unsigned short ushortx4 __attribute__((ext_vector_type(4)));

constexpr int NN = 8192;
constexpr int MM = 8192;
constexpr int DD = 512;
constexpr float SCALE2 = 0.0637587160f;         // log2(e) / sqrt(512), folded into Q

#define NEG_INF (-__builtin_inff())

#if defined(__has_builtin)
#if __has_builtin(__builtin_amdgcn_exp2f)
#define EXP2F(x) __builtin_amdgcn_exp2f(x)
#else
#define EXP2F(x) exp2f(x)
#endif
#else
#define EXP2F(x) exp2f(x)
#endif

DEV unsigned short f2bf(float f) {              // RNE fp32 -> bf16 bits
  unsigned u = __builtin_bit_cast(unsigned, f);
  return (unsigned short)((u + 0x7FFFu + ((u >> 16) & 1u)) >> 16);
}
DEV float bf2f(unsigned short h) {
  unsigned u = ((unsigned)h) << 16;
  return __builtin_bit_cast(float, u);
}

// TBAA-safe vector ld/st (memcpy compiles to single b128/b64 with assumed alignment)
DEV short8 ld_s8(const void* p) {
  short8 v; __builtin_memcpy(&v, __builtin_assume_aligned(p, 16), 16); return v;
}
DEV uintx4 ld_u4(const void* p) {
  uintx4 v; __builtin_memcpy(&v, __builtin_assume_aligned(p, 16), 16); return v;
}
DEV void st_u4(void* p, uintx4 v) {
  __builtin_memcpy(__builtin_assume_aligned(p, 16), &v, 16);
}
DEV void st_us4(void* p, ushortx4 v) {
  __builtin_memcpy(__builtin_assume_aligned(p, 8), &v, 8);
}
DEV float4 ld_f4(const void* p) {
  float4 v; __builtin_memcpy(&v, __builtin_assume_aligned(p, 16), 16); return v;
}

DEV void async_lds16(const void* g, const void* l) {  // global -> LDS DMA, 16B/lane
  __builtin_amdgcn_global_load_lds(
      (const __attribute__((address_space(1))) unsigned int*)g,
      (__attribute__((address_space(3))) unsigned int*)l, 16, 0, 0);
}

// ---------------------------------------------------------------------------
// Kernel 0: W fp32 -> bf16, once. grid (128, 1, 3), block 256, 8 elems/thread.
// ---------------------------------------------------------------------------
__global__ void prep_w(const float* __restrict__ Wq, const float* __restrict__ Wk,
                       const float* __restrict__ Wv, unsigned short* __restrict__ Wb) {
  const int z = blockIdx.z;
  const float* src = (z == 0) ? Wq : (z == 1) ? Wk : Wv;
  unsigned short* dst = Wb + (size_t)z * DD * DD;
  size_t idx = ((size_t)blockIdx.x * 256 + threadIdx.x) * 8;
  float4 a = ld_f4(src + idx);
  float4 b = ld_f4(src + idx + 4);
  ushortx4 lo = {f2bf(a.x), f2bf(a.y), f2bf(a.z), f2bf(a.w)};
  ushortx4 hi = {f2bf(b.x), f2bf(b.y), f2bf(b.z), f2bf(b.w)};
  st_us4(dst + idx, lo);
  st_us4(dst + idx + 4, hi);
}

// ---------------------------------------------------------------------------
// Kernel 1: QKV projection. grid (128, 2, 3), block 256. Tile 64 rows x 256 cols,
// BK=64. LDS xor-swizzled (chunk ^= row&7) -> conflict-free b128 frag reads.
// z=0: Q (scaled by SCALE2) -> Qb[N][D]; z=1: K -> Kb[M][D]; z=2: V -> VTb[D][M].
// ---------------------------------------------------------------------------
__global__ __launch_bounds__(256, 2)
void qkv_proj(const float* __restrict__ x, const float* __restrict__ dx,
              const unsigned short* __restrict__ Wb,
              const float* __restrict__ bq, const float* __restrict__ bk,
              const float* __restrict__ bv,
              unsigned short* __restrict__ Qb, unsigned short* __restrict__ Kb,
              unsigned short* __restrict__ VTb) {
  const int z = blockIdx.z;
  const float* A = (z == 0) ? x : dx;
  const unsigned short* W = Wb + (size_t)z * DD * DD;
  const float* bias = (z == 0) ? bq : (z == 1) ? bk : bv;

  const int r0 = blockIdx.x * 64;
  const int c0 = blockIdx.y * 256;
  const int tid = threadIdx.x;
  const int lane = tid & 63;
  const int wave = tid >> 6;
  const int lr = lane & 15;
  const int quad = lane >> 4;

  __shared__ __align__(16) unsigned short As[64 * 64];   //  8 KB
  __shared__ __align__(16) unsigned short Ws[256 * 64];  // 32 KB

  floatx4 o[16];
#pragma unroll
  for (int i = 0; i < 16; ++i) o[i] = {0.f, 0.f, 0.f, 0.f};

  for (int k0 = 0; k0 < DD; k0 += 64) {
    // stage A tile (fp32 -> bf16): 64 rows x 64 k, 4 float4 per thread
#pragma unroll
    for (int i = 0; i < 4; ++i) {
      int idx = i * 256 + tid;
      int r = idx >> 4, c4 = idx & 15;
      float4 v = ld_f4(A + (size_t)(r0 + r) * DD + k0 + c4 * 4);
      ushortx4 pk = {f2bf(v.x), f2bf(v.y), f2bf(v.z), f2bf(v.w)};
      st_us4(&As[r * 64 + (((c4 >> 1) ^ (r & 7)) * 8) + (c4 & 1) * 4], pk);
    }
    // stage W tile (bf16, no convert): 256 rows x 64 k, 8 x 16B per thread
#pragma unroll
    for (int i = 0; i < 8; ++i) {
      int idx = i * 256 + tid;
      int r = idx >> 3, c = idx & 7;
      uintx4 v = ld_u4(W + (size_t)(c0 + r) * DD + k0 + c * 8);
      st_u4(&Ws[r * 64 + ((c ^ (r & 7)) * 8)], v);
    }
    __syncthreads();

    short8 a[2];
#pragma unroll
    for (int ks = 0; ks < 2; ++ks)
      a[ks] = ld_s8(&As[(wave * 16 + lr) * 64 + (((ks * 4 + quad) ^ (lr & 7)) * 8)]);
#pragma unroll
    for (int ct = 0; ct < 16; ++ct) {
#pragma unroll
      for (int ks = 0; ks < 2; ++ks) {
        short8 b = ld_s8(&Ws[(ct * 16 + lr) * 64 + (((ks * 4 + quad) ^ (lr & 7)) * 8)]);
        o[ct] = __builtin_amdgcn_mfma_f32_16x16x32_bf16(a[ks], b, o[ct], 0, 0, 0);
      }
    }
    __syncthreads();
  }

  // epilogue: bias (+Q scale), store. C layout: col = lr, row = quad*4 + reg.
#pragma unroll
  for (int ct = 0; ct < 16; ++ct) {
    int col = c0 + ct * 16 + lr;
    float bv_ = bias[col];
    int rowb = r0 + wave * 16 + quad * 4;
    if (z == 2) {  // VT[col][row], 4 consecutive rows -> 8B store
      ushortx4 pk = {f2bf(o[ct][0] + bv_), f2bf(o[ct][1] + bv_),
                     f2bf(o[ct][2] + bv_), f2bf(o[ct][3] + bv_)};
      st_us4(VTb + (size_t)col * MM + rowb, pk);
    } else {
      unsigned short* Outp = (z == 0) ? Qb : Kb;
      float sc = (z == 0) ? SCALE2 : 1.f;
#pragma unroll
      for (int r = 0; r < 4; ++r)
        Outp[(size_t)(rowb + r) * DD + col] = f2bf((o[ct][r] + bv_) * sc);
    }
  }
}

// ---------------------------------------------------------------------------
// Kernel 2: flash attention. 1-D grid (N/128 * SPLITS_), block 512 (8 waves),
// 1 block/CU (LDS 86,560 B). split = lin & (SPLITS_-1): round-robin XCD = lin%8
// pins each XCD to one split -> its 2 MB K slice is L2-resident.
// Per iter (BM=64), R3's proven 4-barrier order scaled to BN=128:
//   issue K DMA -> BAR1 (K vis) -> S (wave w: its 16 q-rows x 64 m) -> BAR2
//   (K free) -> issue VT DMA into the aliased region -> softmax + P/alpha/flag
//   -> BAR3 (VT+P vis; VT latency hidden under softmax) -> rescale + PV
//   (d-split: wave w covers d-cols 64w..64w+64 x all 128 rows) -> BAR4.
// Register budget: qf 64 + o 128 acc + pa4/vf transients -> no spill at 512x2.
// ---------------------------------------------------------------------------
template <int SPLITS_, int LOG2S_>
__global__ __launch_bounds__(512, 2)
void flash_attn(const unsigned short* __restrict__ Qb,
                const unsigned short* __restrict__ Kb,
                const unsigned short* __restrict__ VTb,
                unsigned short* __restrict__ Opart,
                float* __restrict__ Mpart, float* __restrict__ Lpart) {
  constexpr int MT = MM / SPLITS_;
  constexpr int ITERS = MT / 64;
  const int lin = blockIdx.x;
  const int split = lin & (SPLITS_ - 1);
  const int n0 = (lin >> LOG2S_) * 128;
  const int m_begin = split * MT;

  const int tid = threadIdx.x;
  const int lane = tid & 63;
  const int wave = tid >> 6;   // 0..7
  const int lr = lane & 15;
  const int quad = lane >> 4;

  // sK: K phase rows stride 520 us (1024B DMA row + 16B pad); VT phase (aliased)
  // rows stride 64 us with chunk^=(row&7) swizzle folded into DMA source addrs.
  __shared__ __align__(16) unsigned short sK[64 * 520];    // 66,560 B
  __shared__ __align__(16) unsigned short sP[128 * 76];    // 19,456 B
  __shared__ __align__(16) float sAlpha[128];              //    512 B
  __shared__ int sFlag[8];                                 //     32 B

  // resident Q fragments: wave's 16 rows x 512 k (64 VGPRs), pre-scaled by SCALE2
  short8 qf[16];
  {
    const unsigned short* qptr = Qb + (size_t)(n0 + wave * 16 + lr) * DD + quad * 8;
#pragma unroll
    for (int ks = 0; ks < 16; ++ks) qf[ks] = ld_s8(qptr + ks * 32);
  }

  // VT DMA per-lane source geometry (swizzle in source, dest lane-contiguous):
  // group g = wave*8+j covers VT d-rows 8g..8g+7 -> LDS us [g*512, g*512+512).
  // lane i: LDS row r = 8g + (i>>3), chunk c' = i&7; source chunk c = c' ^ (r&7).
  const int vrb = lane >> 3;                               // 0..7
  const int vcb = ((lane & 7) ^ vrb) * 8;                  // r&7 == vrb
  const unsigned short* vsrc0 = VTb + (size_t)(wave * 64 + vrb) * MM + vcb;
  unsigned short* vdst0 = &sK[wave * 8 * 512];

  floatx4 o[32];  // [rt*4+ct] : O rows n0+rt*16+quad*4+reg, col wave*64+ct*16+lr
#pragma unroll
  for (int i = 0; i < 32; ++i) o[i] = {0.f, 0.f, 0.f, 0.f};
  float mrow[4] = {NEG_INF, NEG_INF, NEG_INF, NEG_INF};
  float lrow[4] = {0.f, 0.f, 0.f, 0.f};

  for (int it = 0; it < ITERS; ++it) {
    const int m0 = m_begin + it * 64;

    // ---- stage K tile: 8 rows per wave, one DMA per row (64 lanes x 16B = 1024B)
#pragma unroll
    for (int i = 0; i < 8; ++i) {
      const int r = wave * 8 + i;  // wave-uniform LDS dest
      async_lds16(Kb + (size_t)(m0 + r) * DD + lane * 8, &sK[r * 520]);
    }
    __syncthreads();  // BAR1: K visible (region free since BAR4 of prev iter)

    // ---- S = Q K^T (wave: its 16 rows x 64 cols), logits already in log2 units
    floatx4 s[4];
#pragma unroll
    for (int ct = 0; ct < 4; ++ct) s[ct] = {0.f, 0.f, 0.f, 0.f};
#pragma unroll
    for (int ks = 0; ks < 16; ++ks) {
      const unsigned short* kb = &sK[ks * 32 + quad * 8];
#pragma unroll
      for (int ct = 0; ct < 4; ++ct) {
        short8 b = ld_s8(kb + (ct * 16 + lr) * 520);
        s[ct] = __builtin_amdgcn_mfma_f32_16x16x32_bf16(qf[ks], b, s[ct], 0, 0, 0);
      }
    }
    __syncthreads();  // BAR2: all waves done reading K region

    // ---- stage VT tile via DMA into aliased region (latency hidden by softmax)
    {
      const unsigned short* src = vsrc0 + m0;
#pragma unroll
      for (int j = 0; j < 8; ++j)
        async_lds16(src + (size_t)j * 8 * MM, vdst0 + j * 512);
    }

    // ---- online softmax (rows quad*4+r, cols across the 16 lanes of the quad)
    float alpha[4];
#pragma unroll
    for (int r = 0; r < 4; ++r) {
      float mx = fmaxf(fmaxf(s[0][r], s[1][r]), fmaxf(s[2][r], s[3][r]));
      mx = fmaxf(mx, __shfl_xor(mx, 1));
      mx = fmaxf(mx, __shfl_xor(mx, 2));
      mx = fmaxf(mx, __shfl_xor(mx, 4));
      mx = fmaxf(mx, __shfl_xor(mx, 8));
      float mnew = fmaxf(mrow[r], mx);
      alpha[r] = EXP2F(mrow[r] - mnew);  // first iter: exp2(-inf) = 0
      mrow[r] = mnew;
      float rs = 0.f;
#pragma unroll
      for (int ct = 0; ct < 4; ++ct) {
        float p = EXP2F(s[ct][r] - mnew);
        s[ct][r] = p;
        rs += p;
      }
      rs += __shfl_xor(rs, 1);
      rs += __shfl_xor(rs, 2);
      rs += __shfl_xor(rs, 4);
      rs += __shfl_xor(rs, 8);
      lrow[r] = lrow[r] * alpha[r] + rs;
    }
    {
      bool nd = (alpha[0] < 1.f) || (alpha[1] < 1.f) || (alpha[2] < 1.f) || (alpha[3] < 1.f);
      int any = __any(nd) ? 1 : 0;
      if (lane == 0) sFlag[wave] = any;
      if (lr == 0) {
#pragma unroll
        for (int r = 0; r < 4; ++r) sAlpha[wave * 16 + quad * 4 + r] = alpha[r];
      }
    }

    // ---- P (C layout) -> shared LDS bf16 [128][76]
#pragma unroll
    for (int ct = 0; ct < 4; ++ct)
#pragma unroll
      for (int r = 0; r < 4; ++r)
        sP[(wave * 16 + quad * 4 + r) * 76 + ct * 16 + lr] = f2bf(s[ct][r]);

    __syncthreads();  // BAR3: drains VT DMA; P + alphas + flags visible

    // ---- rescale O per 16-row group (flag gated, wave-uniform branch)
#pragma unroll
    for (int rt = 0; rt < 8; ++rt) {
      if (sFlag[rt]) {
        float4 t = ld_f4(&sAlpha[rt * 16 + quad * 4]);
#pragma unroll
        for (int ct = 0; ct < 4; ++ct) {
          o[rt * 4 + ct][0] *= t.x;
          o[rt * 4 + ct][1] *= t.y;
          o[rt * 4 + ct][2] *= t.z;
          o[rt * 4 + ct][3] *= t.w;
        }
      }
    }

    // ---- O += P V (d-split): A = P rows (all 128) from LDS, B = VT (aliased LDS)
#pragma unroll
    for (int ks = 0; ks < 2; ++ks) {
#pragma unroll
      for (int rth = 0; rth < 2; ++rth) {
        short8 pa[4];
#pragma unroll
        for (int i = 0; i < 4; ++i)
          pa[i] = ld_s8(&sP[((rth * 4 + i) * 16 + lr) * 76 + ks * 32 + quad * 8]);
#pragma unroll
        for (int ct = 0; ct < 4; ++ct) {
          const int r = wave * 64 + ct * 16 + lr;  // VT LDS row = d-col; r&7 == lr&7
          short8 b = ld_s8(&sK[r * 64 + (((ks * 4 + quad) ^ (lr & 7)) * 8)]);
#pragma unroll
          for (int i = 0; i < 4; ++i)
            o[(rth * 4 + i) * 4 + ct] = __builtin_amdgcn_mfma_f32_16x16x32_bf16(
                pa[i], b, o[(rth * 4 + i) * 4 + ct], 0, 0, 0);
        }
      }
    }
    __syncthreads();  // BAR4: aliased region + sP/sAlpha free for next iter
  }

  // ---- epilogue: unnormalized partials (d-split layout)
  unsigned short* op = Opart + (size_t)split * NN * DD;
#pragma unroll
  for (int rt = 0; rt < 8; ++rt)
#pragma unroll
    for (int ct = 0; ct < 4; ++ct) {
      int row = n0 + rt * 16 + quad * 4;
      int col = wave * 64 + ct * 16 + lr;
#pragma unroll
      for (int r = 0; r < 4; ++r)
        op[(size_t)(row + r) * DD + col] = f2bf(o[rt * 4 + ct][r]);
    }
  const int grow = n0 + wave * 16 + quad * 4;
  if (lr == 0) {
#pragma unroll
    for (int r = 0; r < 4; ++r) {
      Mpart[split * NN + grow + r] = mrow[r];
      Lpart[split * NN + grow + r] = lrow[r];
    }
  }
}

// ---------------------------------------------------------------------------
// Kernel 3: exact softmax merge of SPLITS partials. 8 elems/thread, b128 I/O.
// grid (N*D/2048), block 256.
// ---------------------------------------------------------------------------
template <int SPLITS_>
__global__ void combine_kernel(const unsigned short* __restrict__ Op,
                               const float* __restrict__ Mp,
                               const float* __restrict__ Lp,
                               float* __restrict__ out) {
  constexpr size_t NDv = (size_t)NN * DD;
  size_t base = ((size_t)blockIdx.x * 256 + threadIdx.x) * 8;
  int n = (int)(base >> 9);
  float mv[SPLITS_];
  float ms = NEG_INF;
#pragma unroll
  for (int s = 0; s < SPLITS_; ++s) {
    mv[s] = Mp[s * NN + n];
    ms = fmaxf(ms, mv[s]);
  }
  float num[8];
#pragma unroll
  for (int j = 0; j < 8; ++j) num[j] = 0.f;
  float den = 0.f;
#pragma unroll
  for (int s = 0; s < SPLITS_; ++s) {
    float w = EXP2F(mv[s] - ms);
    den += w * Lp[s * NN + n];
    uintx4 u = ld_u4(Op + s * NDv + base);
#pragma unroll
    for (int j = 0; j < 4; ++j) {
      num[2 * j]     += w * bf2f((unsigned short)(u[j] & 0xffffu));
      num[2 * j + 1] += w * bf2f((unsigned short)(u[j] >> 16));
    }
  }
  float inv = 1.f / den;
  float4 o0 = {num[0] * inv, num[1] * inv, num[2] * inv, num[3] * inv};
  float4 o1 = {num[4] * inv, num[5] * inv, num[6] * inv, num[7] * inv};
  __builtin_memcpy(__builtin_assume_aligned(out + base, 16), &o0, 16);
  __builtin_memcpy(__builtin_assume_aligned(out + base + 4, 16), &o1, 16);
}

// ---------------------------------------------------------------------------
extern "C" void kernel_launch(void* const* d_in, const int* in_sizes, int n_in,
                              void* d_out, int out_size, void* d_ws, size_t ws_size,
                              hipStream_t stream) {
  const float* x  = (const float*)d_in[0];
  const float* dx = (const float*)d_in[1];
  const float* Wq = (const float*)d_in[2];
  const float* bq = (const float*)d_in[3];
  const float* Wk = (const float*)d_in[4];
  const float* bk = (const float*)d_in[5];
  const float* Wv = (const float*)d_in[6];
  const float* bv = (const float*)d_in[7];
  float* out = (float*)d_out;

  const size_t ND = (size_t)NN * DD;          // 4,194,304
  const size_t WBE = (size_t)3 * DD * DD;     //   786,432
  unsigned short* Qb  = (unsigned short*)d_ws;     // bf16, ND (pre-scaled)
  unsigned short* Kb  = Qb + ND;                   // bf16, ND
  unsigned short* VTb = Kb + ND;                   // bf16, ND (transposed V)
  unsigned short* Wb  = VTb + ND;                  // bf16, 3*D*D
  unsigned short* Op  = Wb + WBE;                  // bf16, splits*ND partial O

  auto bytes_for = [&](size_t S) {
    return (3 * ND + WBE + S * ND) * 2 + S * (size_t)NN * 8;
  };
  const int splits = (ws_size >= bytes_for(4)) ? 4 : 2;  // ws_size fixed -> same every call
  float* Mp = (float*)(Op + (size_t)splits * ND);
  float* Lp = Mp + (size_t)splits * NN;

  hipLaunchKernelGGL(prep_w, dim3(DD * DD / 2048, 1, 3), dim3(256), 0, stream,
                     Wq, Wk, Wv, Wb);
  hipLaunchKernelGGL(qkv_proj, dim3(NN / 64, 2, 3), dim3(256), 0, stream,
                     x, dx, Wb, bq, bk, bv, Qb, Kb, VTb);
  if (splits == 4) {
    hipLaunchKernelGGL((flash_attn<4, 2>), dim3(NN / 128 * 4), dim3(512), 0, stream,
                       Qb, Kb, VTb, Op, Mp, Lp);
    hipLaunchKernelGGL(combine_kernel<4>, dim3((unsigned)(ND / 2048)), dim3(256), 0, stream,
                       Op, Mp, Lp, out);
  } else {
    hipLaunchKernelGGL((flash_attn<2, 1>), dim3(NN / 128 * 2), dim3(512), 0, stream,
                       Qb, Kb, VTb, Op, Mp, Lp);
    hipLaunchKernelGGL(combine_kernel<2>, dim3((unsigned)(ND / 2048)), dim3(256), 0, stream,
                       Op, Mp, Lp, out);
  }
}